// Round 1
// baseline (315.209 us; speedup 1.0000x reference)
//
#include <hip/hip_runtime.h>
#include <hip/hip_bf16.h>

// ---------- types / helpers ----------
typedef __attribute__((ext_vector_type(8))) short short8;     // 8 bf16 = 4 VGPRs (MFMA A/B frag)
typedef __attribute__((ext_vector_type(4))) float f32x4;      // MFMA C/D frag

__device__ __forceinline__ float bf2f(unsigned short s) {
    union { unsigned int u; float f; } v; v.u = ((unsigned int)s) << 16; return v.f;
}
__device__ __forceinline__ unsigned short f2bf(float f) {  // round-to-nearest-even
    union { float f; unsigned int u; } v; v.f = f;
    unsigned int u = v.u;
    unsigned int r = (u + 0x7FFFu + ((u >> 16) & 1u)) >> 16;
    return (unsigned short)r;
}
__device__ __forceinline__ void gload_lds16(const void* g, void* l) {
    // async global->LDS, 16B/lane; LDS dest = wave-uniform base + lane*16
    __builtin_amdgcn_global_load_lds((const __attribute__((address_space(1))) void*)g,
                                     (__attribute__((address_space(3))) void*)l, 16, 0, 0);
}

// ---------- constants ----------
#define BATCH 256
#define CHAN  768
#define HW    196
#define SPS   196
#define HID   512
#define MROWS 50176   // BATCH*SPS
#define K1    1536    // 2*CHAN

// ---------- weight prep ----------
// in [K][N] fp32 -> out [N][K] bf16  (N-major so B-frag reads are contiguous)
__global__ void transpose_cast(const float* __restrict__ in, unsigned short* __restrict__ out,
                               int K, int N) {
    int idx = blockIdx.x * 256 + threadIdx.x;
    if (idx >= K * N) return;
    int n = idx / K, k = idx - n * K;
    out[idx] = f2bf(in[(size_t)k * N + n]);
}
__global__ void cast_copy(const float* __restrict__ in, unsigned short* __restrict__ out, int n) {
    int i = blockIdx.x * 256 + threadIdx.x;
    if (i < n) out[i] = f2bf(in[i]);
}

// ---------- gather: x[b, c, pos] -> feats[(b,s), 0:768]=x[..ix], [768:1536]=x[..iy], bf16 ----------
__global__ __launch_bounds__(256) void gather_feats(const float* __restrict__ x,
                                                    const int* __restrict__ pxs,
                                                    const int* __restrict__ pys,
                                                    unsigned short* __restrict__ feats) {
    __shared__ float lds[64 * 197];   // pitch 197: stride-5 banks, conflict-free
    int chunk = blockIdx.x;           // 0..11 (64-channel chunk)
    int b     = blockIdx.y;           // 0..255
    int c0 = chunk * 64;
    const float* xb = x + ((size_t)b * CHAN + c0) * HW;
    for (int t = threadIdx.x; t < 64 * HW; t += 256) {
        int j = t / HW, p = t - j * HW;
        lds[j * 197 + p] = xb[t];     // coalesced read of 64 full channels
    }
    __syncthreads();
    int w = threadIdx.x >> 6, lane = threadIdx.x & 63;
    for (int s = w; s < SPS; s += 4) {
        int base = (b * SPS + s) * 2;
        int ix = pxs[base] * 14 + pxs[base + 1];
        int iy = pys[base] * 14 + pys[base + 1];
        size_t ro = (size_t)(b * SPS + s) * K1;
        feats[ro + c0 + lane]        = f2bf(lds[lane * 197 + ix]);  // 128B coalesced store
        feats[ro + CHAN + c0 + lane] = f2bf(lds[lane * 197 + iy]);
    }
}

// ---------- 128x128 bf16 MFMA GEMM: C = relu(A @ Bt^T + bias), A[M][K], Bt[N][K] ----------
__global__ __launch_bounds__(256) void gemm_bias_relu(const unsigned short* __restrict__ A,
                                                      const unsigned short* __restrict__ Bt,
                                                      const float* __restrict__ bias,
                                                      unsigned short* __restrict__ C,
                                                      int M, int Kd, int N, int doRelu) {
    __shared__ unsigned short Asm[128 * 64];
    __shared__ unsigned short Bsm[128 * 64];
    int t = threadIdx.x;
    int w = t >> 6, lane = t & 63;
    int wr = w >> 1, wc = w & 1;             // 2x2 wave grid, each wave 64x64
    int lr = lane & 15, lk = lane >> 4;
    int mBase = blockIdx.x * 128;
    int nBase = blockIdx.y * 128;
    f32x4 acc[4][4] = {};
    int nK = Kd >> 6;
    for (int kt = 0; kt < nK; ++kt) {
        int k0 = kt * 64;
        __syncthreads();
        #pragma unroll
        for (int i = 0; i < 4; ++i) {
            int linear = i * 256 + t;          // 1024 lane-loads x 16B = 32KB (A+B)
            int row  = linear >> 3;            // 8 x 16B per 128B row (BK=64 bf16)
            int colb = (linear & 7) * 16;
            gload_lds16((const char*)(A  + ((size_t)(mBase + row) * Kd + k0)) + colb,
                        (char*)Asm + i * 4096 + w * 1024);
            gload_lds16((const char*)(Bt + ((size_t)(nBase + row) * Kd + k0)) + colb,
                        (char*)Bsm + i * 4096 + w * 1024);
        }
        __syncthreads();                       // vmcnt(0) drain inserted by compiler
        #pragma unroll
        for (int kk = 0; kk < 2; ++kk) {
            short8 af[4], bfr[4];
            #pragma unroll
            for (int m = 0; m < 4; ++m)
                af[m] = *(const short8*)(Asm + (wr * 64 + m * 16 + lr) * 64 + kk * 32 + lk * 8);
            #pragma unroll
            for (int n = 0; n < 4; ++n)
                bfr[n] = *(const short8*)(Bsm + (wc * 64 + n * 16 + lr) * 64 + kk * 32 + lk * 8);
            #pragma unroll
            for (int m = 0; m < 4; ++m)
                #pragma unroll
                for (int n = 0; n < 4; ++n)
                    acc[m][n] = __builtin_amdgcn_mfma_f32_16x16x32_bf16(af[m], bfr[n], acc[m][n], 0, 0, 0);
        }
    }
    // epilogue: bias + relu + bf16 store.  C row=(lane>>4)*4+j, col=lane&15 (m89-verified)
    #pragma unroll
    for (int n = 0; n < 4; ++n) {
        int c = nBase + wc * 64 + n * 16 + lr;
        float bv = bias[c];
        #pragma unroll
        for (int m = 0; m < 4; ++m) {
            int r0 = mBase + wr * 64 + m * 16 + lk * 4;
            #pragma unroll
            for (int j = 0; j < 4; ++j) {
                float v = acc[m][n][j] + bv;
                if (doRelu) v = fmaxf(v, 0.f);
                C[(size_t)(r0 + j) * N + c] = f2bf(v);
            }
        }
    }
}

// ---------- final: pred = h2 @ W3 + b3 (wave-per-row), plus deltaxy ----------
__global__ __launch_bounds__(256) void final_pred(const unsigned short* __restrict__ h2,
                                                  const unsigned short* __restrict__ W3b,
                                                  const float* __restrict__ b3,
                                                  const int* __restrict__ pxs,
                                                  const int* __restrict__ pys,
                                                  float* __restrict__ out) {
    int w = threadIdx.x >> 6, lane = threadIdx.x & 63;
    int waveId = blockIdx.x * 4 + w;
    float wf[16];
    {
        const unsigned short* p = W3b + lane * 16;   // k = lane*8..+8, o=0,1 interleaved
        #pragma unroll
        for (int e = 0; e < 16; ++e) wf[e] = bf2f(p[e]);
    }
    float bb0 = b3[0], bb1 = b3[1];
    int stride = gridDim.x * 4;
    for (int r = waveId; r < MROWS; r += stride) {
        short8 a = *(const short8*)(h2 + (size_t)r * HID + lane * 8);  // 64 lanes = full row, coalesced
        float p0 = 0.f, p1 = 0.f;
        #pragma unroll
        for (int e = 0; e < 8; ++e) {
            float f = bf2f((unsigned short)a[e]);
            p0 += f * wf[2 * e]; p1 += f * wf[2 * e + 1];
        }
        #pragma unroll
        for (int m = 1; m < 64; m <<= 1) {
            p0 += __shfl_xor(p0, m);
            p1 += __shfl_xor(p1, m);
        }
        if (lane == 0) {
            out[(size_t)r * 2 + 0] = p0 + bb0;
            out[(size_t)r * 2 + 1] = p1 + bb1;
        }
    }
    int tid = blockIdx.x * 256 + threadIdx.x;
    for (int i = tid; i < MROWS * 2; i += gridDim.x * 256)
        out[MROWS * 2 + i] = (float)(pxs[i] - pys[i]) + 13.0f;   // (H-1)=13
}

// ---------- launch ----------
extern "C" void kernel_launch(void* const* d_in, const int* in_sizes, int n_in,
                              void* d_out, int out_size, void* d_ws, size_t ws_size,
                              hipStream_t stream) {
    const float* x  = (const float*)d_in[0];
    const float* W1 = (const float*)d_in[1];
    const float* b1 = (const float*)d_in[2];
    const float* W2 = (const float*)d_in[3];
    const float* b2 = (const float*)d_in[4];
    const float* W3 = (const float*)d_in[5];
    const float* b3 = (const float*)d_in[6];
    const int*  pxs = (const int*)d_in[7];
    const int*  pys = (const int*)d_in[8];
    float* out = (float*)d_out;
    char* ws = (char*)d_ws;

    // ws layout (bytes); total needed = 207,620,096 (~198 MB)
    unsigned short* W1t   = (unsigned short*)(ws + 0);          // 512x1536 bf16 = 1,572,864
    unsigned short* W2t   = (unsigned short*)(ws + 1572864);    // 512x512  bf16 =   524,288
    unsigned short* W3b   = (unsigned short*)(ws + 2097152);    // 512x2    bf16 =     2,048
    unsigned short* h1    = (unsigned short*)(ws + 2099200);    // 50176x512 bf16 = 51,380,224
    unsigned short* feats = (unsigned short*)(ws + 53479424);   // 50176x1536 bf16 = 154,140,672
    unsigned short* h2    = feats;                              // alias: feats dead after GEMM1

    transpose_cast<<<(K1 * HID + 255) / 256, 256, 0, stream>>>(W1, W1t, K1, HID);
    transpose_cast<<<(HID * HID + 255) / 256, 256, 0, stream>>>(W2, W2t, HID, HID);
    cast_copy<<<4, 256, 0, stream>>>(W3, W3b, HID * 2);
    gather_feats<<<dim3(12, BATCH), 256, 0, stream>>>(x, pxs, pys, feats);
    gemm_bias_relu<<<dim3(MROWS / 128, HID / 128), 256, 0, stream>>>(feats, W1t, b1, h1, MROWS, K1, HID, 1);
    gemm_bias_relu<<<dim3(MROWS / 128, HID / 128), 256, 0, stream>>>(h1, W2t, b2, h2, MROWS, HID, HID, 1);
    final_pred<<<784, 256, 0, stream>>>(h2, W3b, b3, pxs, pys, out);
}

// Round 2
// 294.955 us; speedup vs baseline: 1.0687x; 1.0687x over previous
//
#include <hip/hip_runtime.h>
#include <hip/hip_bf16.h>

// ---------- types / helpers ----------
typedef __attribute__((ext_vector_type(8))) short short8;     // 8 bf16 = 4 VGPRs (MFMA A/B frag)
typedef __attribute__((ext_vector_type(4))) float f32x4;      // MFMA C/D frag

__device__ __forceinline__ float bf2f(unsigned short s) {
    union { unsigned int u; float f; } v; v.u = ((unsigned int)s) << 16; return v.f;
}
__device__ __forceinline__ unsigned short f2bf(float f) {  // round-to-nearest-even
    union { float f; unsigned int u; } v; v.f = f;
    unsigned int u = v.u;
    unsigned int r = (u + 0x7FFFu + ((u >> 16) & 1u)) >> 16;
    return (unsigned short)r;
}
__device__ __forceinline__ void gload_lds16(const void* g, void* l) {
    // async global->LDS, 16B/lane; LDS dest = wave-uniform base + lane*16
    __builtin_amdgcn_global_load_lds((const __attribute__((address_space(1))) void*)g,
                                     (__attribute__((address_space(3))) void*)l, 16, 0, 0);
}

// ---------- constants ----------
#define BATCH 256
#define CHAN  768
#define HW    196
#define SPS   196
#define HID   512
#define MROWS 50176   // BATCH*SPS
#define K1    1536    // 2*CHAN

// ---------- weight prep ----------
// in [K][N] fp32 -> out [N][K] bf16  (N-major so B-frag reads are contiguous)
__global__ void transpose_cast(const float* __restrict__ in, unsigned short* __restrict__ out,
                               int K, int N) {
    int idx = blockIdx.x * 256 + threadIdx.x;
    if (idx >= K * N) return;
    int n = idx / K, k = idx - n * K;
    out[idx] = f2bf(in[(size_t)k * N + n]);
}
__global__ void cast_copy(const float* __restrict__ in, unsigned short* __restrict__ out, int n) {
    int i = blockIdx.x * 256 + threadIdx.x;
    if (i < n) out[i] = f2bf(in[i]);
}

// ---------- gather: x[b, c, pos] -> feats[(b,s), 0:768]=x[..ix], [768:1536]=x[..iy], bf16 ----------
__global__ __launch_bounds__(256) void gather_feats(const float* __restrict__ x,
                                                    const int* __restrict__ pxs,
                                                    const int* __restrict__ pys,
                                                    unsigned short* __restrict__ feats) {
    __shared__ float lds[64 * 197];   // pitch 197: stride-5 banks, conflict-free
    int chunk = blockIdx.x;           // 0..11 (64-channel chunk)
    int b     = blockIdx.y;           // 0..255
    int c0 = chunk * 64;
    const float* xb = x + ((size_t)b * CHAN + c0) * HW;
    for (int t = threadIdx.x; t < 64 * HW; t += 256) {
        int j = t / HW, p = t - j * HW;
        lds[j * 197 + p] = xb[t];     // coalesced read of 64 full channels
    }
    __syncthreads();
    int w = threadIdx.x >> 6, lane = threadIdx.x & 63;
    for (int s = w; s < SPS; s += 4) {
        int base = (b * SPS + s) * 2;
        int ix = pxs[base] * 14 + pxs[base + 1];
        int iy = pys[base] * 14 + pys[base + 1];
        size_t ro = (size_t)(b * SPS + s) * K1;
        feats[ro + c0 + lane]        = f2bf(lds[lane * 197 + ix]);  // 128B coalesced store
        feats[ro + CHAN + c0 + lane] = f2bf(lds[lane * 197 + iy]);
    }
}

// ---------- 128x128 bf16 MFMA GEMM, 2-phase double-buffered, XOR-swizzled LDS ----------
// C = relu(A @ Bt^T + bias); A[M][K], Bt[N][K] row-major bf16.
// grid = dim3(N/128, M/128): N fastest -> consecutive blocks share the A-tile (fetch A once).
// LDS tile [128][64 bf16]: slot(row, c) holds global 16B-chunk (c ^ (row&7))  [T2 both-sides swizzle]
__global__ __launch_bounds__(256) void gemm_bias_relu(const unsigned short* __restrict__ A,
                                                      const unsigned short* __restrict__ Bt,
                                                      const float* __restrict__ bias,
                                                      unsigned short* __restrict__ C,
                                                      int M, int Kd, int N, int doRelu) {
    __shared__ unsigned short Asm[2][128 * 64];
    __shared__ unsigned short Bsm[2][128 * 64];
    int t = threadIdx.x;
    int w = t >> 6, lane = t & 63;
    int wr = w >> 1, wc = w & 1;             // 2x2 wave grid, each wave 64x64
    int lr = lane & 15, lk = lane >> 4;
    int mBase = blockIdx.y * 128;
    int nBase = blockIdx.x * 128;
    f32x4 acc[4][4] = {};
    int nK = Kd >> 6;

    // stage one K-tile (A+B) into buffer `buf` with inverse-swizzled global source.
    // linear = i*256+t; row = linear>>3; LDS dest byte = linear*16 = slot(row, linear&7).
    // source chunk = (linear&7) ^ (row&7); note (linear>>3)&7 == lane>>3.
    auto stage = [&](int buf, int kt) {
        int k0 = kt << 6;
        #pragma unroll
        for (int i = 0; i < 4; ++i) {
            int linear = i * 256 + t;
            int row  = linear >> 3;
            int cs   = (linear & 7) ^ (row & 7);    // inverse-swizzled source chunk
            gload_lds16((const char*)(A  + ((size_t)(mBase + row) * Kd + k0 + cs * 8)),
                        (char*)Asm[buf] + i * 4096 + w * 1024);
            gload_lds16((const char*)(Bt + ((size_t)(nBase + row) * Kd + k0 + cs * 8)),
                        (char*)Bsm[buf] + i * 4096 + w * 1024);
        }
    };
    // compute one K-tile from buffer `buf`; swizzled ds_read addresses.
    auto compute = [&](int buf) {
        #pragma unroll
        for (int kk = 0; kk < 2; ++kk) {
            short8 af[4], bfr[4];
            #pragma unroll
            for (int m = 0; m < 4; ++m) {
                int row = wr * 64 + m * 16 + lr;
                int q = (kk * 4 + lk) ^ (row & 7);              // swizzled chunk
                af[m] = *(const short8*)(&Asm[buf][row * 64 + q * 8]);
            }
            #pragma unroll
            for (int n = 0; n < 4; ++n) {
                int row = wc * 64 + n * 16 + lr;
                int q = (kk * 4 + lk) ^ (row & 7);
                bfr[n] = *(const short8*)(&Bsm[buf][row * 64 + q * 8]);
            }
            #pragma unroll
            for (int m = 0; m < 4; ++m)
                #pragma unroll
                for (int n = 0; n < 4; ++n)
                    acc[m][n] = __builtin_amdgcn_mfma_f32_16x16x32_bf16(af[m], bfr[n], acc[m][n], 0, 0, 0);
        }
    };

    stage(0, 0);
    __syncthreads();                 // drains vmcnt(0): tile 0 resident
    int cur = 0;
    for (int kt = 0; kt + 1 < nK; ++kt) {
        stage(cur ^ 1, kt + 1);      // issue next tile's loads; in flight during compute
        compute(cur);
        __syncthreads();             // drains vmcnt(0) (next tile ready) + all lanes done reading cur
        cur ^= 1;
    }
    compute(cur);

    // epilogue: bias + relu + bf16 store.  C row=(lane>>4)*4+j, col=lane&15 (m89-verified)
    #pragma unroll
    for (int n = 0; n < 4; ++n) {
        int c = nBase + wc * 64 + n * 16 + lr;
        float bv = bias[c];
        #pragma unroll
        for (int m = 0; m < 4; ++m) {
            int r0 = mBase + wr * 64 + m * 16 + lk * 4;
            #pragma unroll
            for (int j = 0; j < 4; ++j) {
                float v = acc[m][n][j] + bv;
                if (doRelu) v = fmaxf(v, 0.f);
                C[(size_t)(r0 + j) * N + c] = f2bf(v);
            }
        }
    }
}

// ---------- final: pred = h2 @ W3 + b3 (wave-per-row), plus deltaxy ----------
__global__ __launch_bounds__(256) void final_pred(const unsigned short* __restrict__ h2,
                                                  const unsigned short* __restrict__ W3b,
                                                  const float* __restrict__ b3,
                                                  const int* __restrict__ pxs,
                                                  const int* __restrict__ pys,
                                                  float* __restrict__ out) {
    int w = threadIdx.x >> 6, lane = threadIdx.x & 63;
    int waveId = blockIdx.x * 4 + w;
    float wf[16];
    {
        const unsigned short* p = W3b + lane * 16;   // k = lane*8..+8, o=0,1 interleaved
        #pragma unroll
        for (int e = 0; e < 16; ++e) wf[e] = bf2f(p[e]);
    }
    float bb0 = b3[0], bb1 = b3[1];
    int stride = gridDim.x * 4;
    for (int r = waveId; r < MROWS; r += stride) {
        short8 a = *(const short8*)(h2 + (size_t)r * HID + lane * 8);  // 64 lanes = full row, coalesced
        float p0 = 0.f, p1 = 0.f;
        #pragma unroll
        for (int e = 0; e < 8; ++e) {
            float f = bf2f((unsigned short)a[e]);
            p0 += f * wf[2 * e]; p1 += f * wf[2 * e + 1];
        }
        #pragma unroll
        for (int m = 1; m < 64; m <<= 1) {
            p0 += __shfl_xor(p0, m);
            p1 += __shfl_xor(p1, m);
        }
        if (lane == 0) {
            out[(size_t)r * 2 + 0] = p0 + bb0;
            out[(size_t)r * 2 + 1] = p1 + bb1;
        }
    }
    int tid = blockIdx.x * 256 + threadIdx.x;
    for (int i = tid; i < MROWS * 2; i += gridDim.x * 256)
        out[MROWS * 2 + i] = (float)(pxs[i] - pys[i]) + 13.0f;   // (H-1)=13
}

// ---------- launch ----------
extern "C" void kernel_launch(void* const* d_in, const int* in_sizes, int n_in,
                              void* d_out, int out_size, void* d_ws, size_t ws_size,
                              hipStream_t stream) {
    const float* x  = (const float*)d_in[0];
    const float* W1 = (const float*)d_in[1];
    const float* b1 = (const float*)d_in[2];
    const float* W2 = (const float*)d_in[3];
    const float* b2 = (const float*)d_in[4];
    const float* W3 = (const float*)d_in[5];
    const float* b3 = (const float*)d_in[6];
    const int*  pxs = (const int*)d_in[7];
    const int*  pys = (const int*)d_in[8];
    float* out = (float*)d_out;
    char* ws = (char*)d_ws;

    // ws layout (bytes); total needed = 207,620,096 (~198 MB)
    unsigned short* W1t   = (unsigned short*)(ws + 0);          // 512x1536 bf16 = 1,572,864
    unsigned short* W2t   = (unsigned short*)(ws + 1572864);    // 512x512  bf16 =   524,288
    unsigned short* W3b   = (unsigned short*)(ws + 2097152);    // 512x2    bf16 =     2,048
    unsigned short* h1    = (unsigned short*)(ws + 2099200);    // 50176x512 bf16 = 51,380,224
    unsigned short* feats = (unsigned short*)(ws + 53479424);   // 50176x1536 bf16 = 154,140,672
    unsigned short* h2    = feats;                              // alias: feats dead after GEMM1

    transpose_cast<<<(K1 * HID + 255) / 256, 256, 0, stream>>>(W1, W1t, K1, HID);
    transpose_cast<<<(HID * HID + 255) / 256, 256, 0, stream>>>(W2, W2t, HID, HID);
    cast_copy<<<4, 256, 0, stream>>>(W3, W3b, HID * 2);
    gather_feats<<<dim3(12, BATCH), 256, 0, stream>>>(x, pxs, pys, feats);
    // grid: x = N-tiles (fastest) so consecutive blocks share the A-tile
    gemm_bias_relu<<<dim3(HID / 128, MROWS / 128), 256, 0, stream>>>(feats, W1t, b1, h1, MROWS, K1, HID, 1);
    gemm_bias_relu<<<dim3(HID / 128, MROWS / 128), 256, 0, stream>>>(h1, W2t, b2, h2, MROWS, HID, HID, 1);
    final_pred<<<784, 256, 0, stream>>>(h2, W3b, b3, pxs, pys, out);
}